// Round 1
// baseline (188.747 us; speedup 1.0000x reference)
//
#include <hip/hip_runtime.h>
#include <hip/hip_bf16.h>

// Causal MHA: B=2 N=2048 D=1024 H=16 DH=64. fp32 in/out, bf16 MFMA internal.
// R9 = R8 with the QKV GEMM ported to the 256x256 8-phase schedule
// (T2 LDS XOR-swizzle + T3/T4 counted-vmcnt phases + T5 setprio), grid 16x12,
// 512 threads (8 waves, 2M x 4N), 128 KiB LDS, 1 block/CU. Staging schedule:
// per tile T phases stage {B1(T+1), A1(T+1), B0(T+2), A0(T+2)}; vmcnt(4) at
// tile boundary (vmcnt(0) at tail). Casts fused into one kernel. Flash attn
// and out-projection GEMM unchanged from R8.

typedef __hip_bfloat16 bf16;
typedef short bf16x8 __attribute__((ext_vector_type(8)));   // 4 VGPR (K=32 MFMA A/B)
typedef short bf16x4 __attribute__((ext_vector_type(4)));   // 2 VGPR (K=16 MFMA A/B)
typedef float f32x4 __attribute__((ext_vector_type(4)));    // MFMA C/D frag

#define QSCALE 0.1803368801111204f   // 0.125 * log2(e): S in log2 domain

typedef __attribute__((address_space(3))) unsigned int lds_u32;
typedef const __attribute__((address_space(1))) unsigned int glob_u32;

__device__ __forceinline__ void glds16(const void* g, void* l) {
    __builtin_amdgcn_global_load_lds((glob_u32*)g, (lds_u32*)l, 16, 0, 0);
}

__device__ __forceinline__ short f2bf(float f) {
    __hip_bfloat16 h = __float2bfloat16(f);
    return *reinterpret_cast<short*>(&h);
}

// pack two f32 -> two bf16 (round-to-nearest-up) in one u32: {hi16(b), hi16(a)}
__device__ __forceinline__ unsigned pack_bf16(float a, float b) {
    unsigned au = __builtin_bit_cast(unsigned, a) + 0x8000u;
    unsigned bu = __builtin_bit_cast(unsigned, b) + 0x8000u;
    return __builtin_amdgcn_perm(bu, au, 0x07060302u);  // bytes: b[3],b[2],a[3],a[2]
}

// ---------------- fused cast fp32 -> bf16 for x, W_qkv, W_out ----------------
// ranges are 256-thread-block aligned: no intra-block divergence.
__global__ void cast_all(const float* __restrict__ x, const float* __restrict__ wqkv,
                         const float* __restrict__ wout,
                         bf16* __restrict__ xb, bf16* __restrict__ wqkvb,
                         bf16* __restrict__ woutb) {
    int i = blockIdx.x * blockDim.x + threadIdx.x;   // 0 .. 2097151 (x4 elems)
    const float4* s; short4* d; int o;
    if (i < 1048576)            { s = (const float4*)x;    d = (short4*)xb;    o = i; }
    else if (i < 1048576 + 786432) { s = (const float4*)wqkv; d = (short4*)wqkvb; o = i - 1048576; }
    else                        { s = (const float4*)wout; d = (short4*)woutb; o = i - 1834848 + 32; }
    // NB: 1048576+786432 = 1835008; o = i - 1835008 for wout
    if (i >= 1048576 + 786432) o = i - 1835008;
    float4 f = s[o];
    short4 v;
    v.x = f2bf(f.x); v.y = f2bf(f.y); v.z = f2bf(f.z); v.w = f2bf(f.w);
    d[o] = v;
}

// ---------- QKV GEMM, 256x256 tile, 8-phase counted-vmcnt schedule ----------
// C[4096,3072] = A[4096,1024] @ Bt[3072,1024]^T, scattered to q/k/v [32,2048,64].
// 512 threads = 8 waves (wm in {0,1} -> 128 rows, wn in {0..3} -> 64 cols).
// LDS: As/Bs [2 buf][256][64] bf16 = 64 KiB each. Swizzle: byte offset XOR
// bits {9,10} -> {5,6} (involution; applied on ds_read addr AND pre-applied to
// the per-lane global source so global_load_lds's linear dest lands swizzled).
#define MMAC(mh, nh) do {                                                          \
    _Pragma("unroll")                                                              \
    for (int mt = 0; mt < 4; ++mt) {                                               \
        _Pragma("unroll")                                                          \
        for (int j = 0; j < 2; ++j) {                                              \
            f32x4 c = acc[(mh)*4+mt][(nh)*2+j];                                    \
            c = __builtin_amdgcn_mfma_f32_16x16x32_bf16(af[mt][0], bfr[nh][j][0], c, 0, 0, 0); \
            c = __builtin_amdgcn_mfma_f32_16x16x32_bf16(af[mt][1], bfr[nh][j][1], c, 0, 0, 0); \
            acc[(mh)*4+mt][(nh)*2+j] = c;                                          \
        }                                                                          \
    }                                                                              \
} while (0)

__global__ __launch_bounds__(512, 2)
void gemm256_qkv(const bf16* __restrict__ A, const bf16* __restrict__ Bt,
                 bf16* __restrict__ qp, bf16* __restrict__ kp, bf16* __restrict__ vp) {
    constexpr int K = 1024, NT = K / 64;          // 16 K-tiles of 64
    __shared__ alignas(16) short As[2 * 16384];   // [buf][256][64], 64 KiB
    __shared__ alignas(16) short Bs[2 * 16384];   // 64 KiB

    const int tid  = threadIdx.x;
    const int lane = tid & 63;
    const int wave = tid >> 6;
    const int quad = lane >> 4, l16 = lane & 15;
    const int wm = wave >> 2;        // 0..1: row half
    const int wn = wave & 3;         // 0..3: 64-col strip
    const int hb = wn >> 1;          // B half this wave reads
    const int m0 = blockIdx.x * 256;
    const int n0 = blockIdx.y * 256;

    // staging: thread t's linear 16B dest chunk is (t*16 bytes) in its half;
    // pre-apply the inverse (== same) swizzle to the SOURCE chunk index.
    const int ts    = tid ^ (((tid >> 5) & 1) << 1) ^ (((tid >> 6) & 1) << 2);
    const int tsrow = ts >> 3;           // 0..63
    const int tscol = (ts & 7) * 8;      // elems

    const bf16* Ag = A  + (size_t)(m0 + tsrow) * K + tscol;
    const bf16* Bg = Bt + (size_t)(n0 + tsrow) * K + tscol;
    short* Asl = As + tid * 8;
    short* Bsl = Bs + tid * 8;

    auto stageA = [&](int T, int h) {   // half h (128 rows) of A K-tile T -> buf T&1
        short* d = Asl + (T & 1) * 16384 + h * 8192;
        const bf16* g = Ag + (size_t)(h * 128) * K + T * 64;
        glds16(g, d);
        glds16(g + (size_t)64 * K, d + 4096);
    };
    auto stageB = [&](int T, int h) {
        short* d = Bsl + (T & 1) * 16384 + h * 8192;
        const bf16* g = Bg + (size_t)(h * 128) * K + T * 64;
        glds16(g, d);
        glds16(g + (size_t)64 * K, d + 4096);
    };

    bf16x8 af[4][2];        // A frags: 4 m-frags x 2 k-steps (current mh)
    bf16x8 bfr[2][2][2];    // B frags: [nh][j][ks] - both nh halves kept live
    f32x4  acc[8][4] = {};  // per-wave C: 128 rows x 64 cols

    auto rdA = [&](const char* ab, int mh) {
        #pragma unroll
        for (int mt = 0; mt < 4; ++mt) {
            const int lr = mh * 64 + mt * 16 + l16;
            #pragma unroll
            for (int ks = 0; ks < 2; ++ks) {
                int o = lr * 128 + ks * 64 + quad * 16;
                o ^= (((o >> 9) & 1) << 5) ^ (((o >> 10) & 1) << 6);
                af[mt][ks] = *reinterpret_cast<const bf16x8*>(ab + o);
            }
        }
    };
    auto rdB = [&](const char* bb, int nh) {
        #pragma unroll
        for (int j = 0; j < 2; ++j) {
            const int lr = (wn & 1) * 64 + (nh * 2 + j) * 16 + l16;
            #pragma unroll
            for (int ks = 0; ks < 2; ++ks) {
                int o = lr * 128 + ks * 64 + quad * 16;
                o ^= (((o >> 9) & 1) << 5) ^ (((o >> 10) & 1) << 6);
                bfr[nh][j][ks] = *reinterpret_cast<const bf16x8*>(bb + o);
            }
        }
    };

    // prologue: tile0 fully + tile1 {B0, A0}. Newest 4 loads = tile1's.
    stageA(0, 0); stageA(0, 1); stageB(0, 0); stageB(0, 1);
    stageB(1, 0); stageA(1, 0);
    asm volatile("s_waitcnt vmcnt(4)" ::: "memory");
    __builtin_amdgcn_s_barrier();

    for (int T = 0; T < NT; ++T) {
        const char* ab = (const char*)As + (T & 1) * 32768 + wm * 16384;
        const char* bb = (const char*)Bs + (T & 1) * 32768 + hb * 16384;
        const bool st1 = (T + 1 < NT), st2 = (T + 2 < NT);

        // ---- phase 0: quadrant (mh0, nh0); stage B1(T+1) ----
        rdA(ab, 0);
        rdB(bb, 0);
        if (st1) stageB(T + 1, 1);
        __builtin_amdgcn_s_barrier();
        asm volatile("s_waitcnt lgkmcnt(0)" ::: "memory");
        __builtin_amdgcn_sched_barrier(0);
        __builtin_amdgcn_s_setprio(1);
        MMAC(0, 0);
        __builtin_amdgcn_s_setprio(0);
        __builtin_amdgcn_s_barrier();

        // ---- phase 1: quadrant (mh0, nh1); stage A1(T+1) ----
        rdB(bb, 1);
        if (st1) stageA(T + 1, 1);
        __builtin_amdgcn_s_barrier();
        asm volatile("s_waitcnt lgkmcnt(0)" ::: "memory");
        __builtin_amdgcn_sched_barrier(0);
        __builtin_amdgcn_s_setprio(1);
        MMAC(0, 1);
        __builtin_amdgcn_s_setprio(0);
        __builtin_amdgcn_s_barrier();

        // ---- phase 2: quadrant (mh1, nh1); stage B0(T+2) ----
        rdA(ab, 1);
        if (st2) stageB(T + 2, 0);
        __builtin_amdgcn_s_barrier();
        asm volatile("s_waitcnt lgkmcnt(0)" ::: "memory");
        __builtin_amdgcn_sched_barrier(0);
        __builtin_amdgcn_s_setprio(1);
        MMAC(1, 1);
        __builtin_amdgcn_s_setprio(0);
        __builtin_amdgcn_s_barrier();

        // ---- phase 3: quadrant (mh1, nh0) (frags already live); stage A0(T+2);
        //      counted vmcnt at the tile boundary (never 0 until the tail). ----
        if (st2) stageA(T + 2, 0);
        __builtin_amdgcn_s_setprio(1);
        MMAC(1, 0);
        __builtin_amdgcn_s_setprio(0);
        if (st1) {
            if (st2) asm volatile("s_waitcnt vmcnt(4)" ::: "memory");
            else     asm volatile("s_waitcnt vmcnt(0)" ::: "memory");
            __builtin_amdgcn_s_barrier();
        }
    }

    // ---- epilogue: scatter to q/k/v [b,h,n,dh]; sel uniform per block ----
    const int sel  = n0 >> 10;                  // 0=q, 1=k, 2=v
    const int remb = n0 & 1023;
    bf16* dst = (sel == 0) ? qp : ((sel == 1) ? kp : vp);
    const float scale = (sel == 0) ? QSCALE : 1.0f;
    #pragma unroll
    for (int mt = 0; mt < 8; ++mt) {
        #pragma unroll
        for (int nt = 0; nt < 4; ++nt) {
            #pragma unroll
            for (int r = 0; r < 4; ++r) {
                int gm  = m0 + wm * 128 + mt * 16 + quad * 4 + r;
                int rem = remb + wn * 64 + nt * 16 + l16;
                int h = rem >> 6, dh = rem & 63;
                int b = gm >> 11, nq = gm & 2047;
                dst[((((size_t)b * 16 + h) * 2048) + nq) * 64 + dh] =
                    __float2bfloat16(acc[mt][nt][r] * scale);
            }
        }
    }
}

// ---------- GEMM 128x128: C[M,Nc] = A[M,K] @ Bt[Nc,K]^T (both K-major) -------
// (unchanged; used for the output projection only)
template<int EPI>
__global__ __launch_bounds__(256)
void gemm128(const bf16* __restrict__ A, const bf16* __restrict__ Bt,
             float* __restrict__ Cf,
             bf16* __restrict__ qp, bf16* __restrict__ kp, bf16* __restrict__ vp,
             int K, int Ncols) {
    __shared__ alignas(16) short As[2][4096];   // 8 KB/buf
    __shared__ alignas(16) short Bs[2][4096];

    const int tid = threadIdx.x;
    const int wave = tid >> 6, lane = tid & 63;
    const int quad = lane >> 4, l16 = lane & 15;
    const int wm = wave >> 1, wn = wave & 1;
    const int m0 = blockIdx.x * 128;
    const int n0 = blockIdx.y * 128;

    f32x4 acc[4][4] = {};

    const int srow = tid >> 2;
    const int skk  = (((tid & 3) ^ ((tid >> 3) & 3))) * 8;
    const bf16* Ag = A  + (size_t)(m0 + srow) * K + skk;
    const bf16* Bg = Bt + (size_t)(n0 + srow) * K + skk;
    const size_t rowskip = (size_t)64 * K;
    short* Asl = &As[0][0] + tid * 8;
    short* Bsl = &Bs[0][0] + tid * 8;

    const int xk = (quad ^ ((l16 >> 1) & 3)) * 8;
    const int arow = wm * 64 + l16;
    const int brow = wn * 64 + l16;

    const int KI = K >> 5;
    glds16(Ag, Asl);
    glds16(Ag + rowskip, Asl + 2048);
    glds16(Bg, Bsl);
    glds16(Bg + rowskip, Bsl + 2048);
    __syncthreads();

    int buf = 0;
    for (int ki = 0; ki < KI; ++ki) {
        if (ki + 1 < KI) {
            const bf16* ag = Ag + (ki + 1) * 32;
            const bf16* bg = Bg + (ki + 1) * 32;
            short* ad = Asl + (buf ^ 1) * 4096;
            short* bd = Bsl + (buf ^ 1) * 4096;
            glds16(ag, ad);
            glds16(ag + rowskip, ad + 2048);
            glds16(bg, bd);
            glds16(bg + rowskip, bd + 2048);
        }
        const short* ab = &As[buf][0];
        const short* bb = &Bs[buf][0];
        bf16x8 af[4], bf[4];
        #pragma unroll
        for (int mt = 0; mt < 4; ++mt)
            af[mt] = *reinterpret_cast<const bf16x8*>(ab + (arow + mt * 16) * 32 + xk);
        #pragma unroll
        for (int nt = 0; nt < 4; ++nt)
            bf[nt] = *reinterpret_cast<const bf16x8*>(bb + (brow + nt * 16) * 32 + xk);
        #pragma unroll
        for (int mt = 0; mt < 4; ++mt)
            #pragma unroll
            for (int nt = 0; nt < 4; ++nt)
                acc[mt][nt] = __builtin_amdgcn_mfma_f32_16x16x32_bf16(
                    af[mt], bf[nt], acc[mt][nt], 0, 0, 0);
        __syncthreads();
        buf ^= 1;
    }

    #pragma unroll
    for (int mt = 0; mt < 4; ++mt) {
        #pragma unroll
        for (int nt = 0; nt < 4; ++nt) {
            #pragma unroll
            for (int r = 0; r < 4; ++r) {
                int gm = m0 + wm * 64 + mt * 16 + quad * 4 + r;
                int gn = n0 + wn * 64 + nt * 16 + l16;
                float val = acc[mt][nt][r];
                if (EPI == 0) {
                    int sel = gn >> 10, rem = gn & 1023;
                    int h = rem >> 6, dh = rem & 63;
                    int b = gm >> 11, nq = gm & 2047;
                    if (sel == 0) val *= QSCALE;
                    bf16* dst = (sel == 0) ? qp : ((sel == 1) ? kp : vp);
                    dst[((((size_t)b * 16 + h) * 2048) + nq) * 64 + dh] = __float2bfloat16(val);
                } else {
                    Cf[(size_t)gm * Ncols + gn] = val;
                }
            }
        }
    }
}

// ---------------- flash attention (causal), S^T form, 128-row q-tiles --------
// (unchanged from R8)
__global__ __launch_bounds__(256)
void flash_attn(const bf16* __restrict__ Q, const bf16* __restrict__ K,
                const bf16* __restrict__ V, bf16* __restrict__ O) {
    __shared__ alignas(16) short Ks[2][64][72];   // [buf][key][dh], +8 pad
    __shared__ alignas(16) short Vt[2][64][68];   // [buf][dh][key]

    const int tid = threadIdx.x;
    const int wave = tid >> 6, lane = tid & 63;
    const int quad = lane >> 4, l16 = lane & 15;
    const int bh = blockIdx.x;
    const int yy = blockIdx.y;
    const int qt = (yy < 8) ? yy : (15 - (yy & 7));   // pair y,y+8 -> 34 iters/CU
    const int Q0 = qt * 128;
    const float NEG_INF = -__builtin_inff();

    const bf16* Qb = Q + (size_t)bh * 2048 * 64;
    const bf16* Kb = K + (size_t)bh * 2048 * 64;
    const bf16* Vb = V + (size_t)bh * 2048 * 64;

    // Q B-frags for both strips
    const int qrowA = Q0 + wave * 16 + l16;
    const int qrowB = qrowA + 64;
    const bf16x8 qfA0 = *reinterpret_cast<const bf16x8*>(Qb + (size_t)qrowA * 64 + quad * 8);
    const bf16x8 qfA1 = *reinterpret_cast<const bf16x8*>(Qb + (size_t)qrowA * 64 + 32 + quad * 8);
    const bf16x8 qfB0 = *reinterpret_cast<const bf16x8*>(Qb + (size_t)qrowB * 64 + quad * 8);
    const bf16x8 qfB1 = *reinterpret_cast<const bf16x8*>(Qb + (size_t)qrowB * 64 + 32 + quad * 8);

    float lA = 0.f, lB = 0.f;
    f32x4 oA[4] = {}, oB[4] = {};

    const int krow = tid >> 2;
    const int kcol = (tid & 3) * 16;
    const int kb = (tid & 15) * 4;
    const int db = (tid >> 4) * 4;

    {   // prologue: stage K/V tile j0=0 into buf 0
        bf16x8 a0 = *reinterpret_cast<const bf16x8*>(Kb + (size_t)krow * 64 + kcol);
        bf16x8 a1 = *reinterpret_cast<const bf16x8*>(Kb + (size_t)krow * 64 + kcol + 8);
        bf16x4 L0 = *reinterpret_cast<const bf16x4*>(Vb + (size_t)(kb + 0) * 64 + db);
        bf16x4 L1 = *reinterpret_cast<const bf16x4*>(Vb + (size_t)(kb + 1) * 64 + db);
        bf16x4 L2 = *reinterpret_cast<const bf16x4*>(Vb + (size_t)(kb + 2) * 64 + db);
        bf16x4 L3 = *reinterpret_cast<const bf16x4*>(Vb + (size_t)(kb + 3) * 64 + db);
        *reinterpret_cast<bf16x8*>(&Ks[0][krow][kcol]) = a0;
        *reinterpret_cast<bf16x8*>(&Ks[0][krow][kcol + 8]) = a1;
        #pragma unroll
        for (int j = 0; j < 4; ++j) {
            bf16x4 w; w[0] = L0[j]; w[1] = L1[j]; w[2] = L2[j]; w[3] = L3[j];
            *reinterpret_cast<bf16x4*>(&Vt[0][db + j][kb]) = w;
        }
    }
    __syncthreads();

    int buf = 0;
    // ---- main loop: j0 < Q0, both strips full ----
    for (int j0 = 0; j0 < Q0; j0 += 64) {
        const bf16* Kn = Kb + (size_t)(j0 + 64) * 64;
        const bf16* Vn = Vb + (size_t)(j0 + 64) * 64;
        bf16x8 nk0 = *reinterpret_cast<const bf16x8*>(Kn + (size_t)krow * 64 + kcol);
        bf16x8 nk1 = *reinterpret_cast<const bf16x8*>(Kn + (size_t)krow * 64 + kcol + 8);
        bf16x4 N0 = *reinterpret_cast<const bf16x4*>(Vn + (size_t)(kb + 0) * 64 + db);
        bf16x4 N1 = *reinterpret_cast<const bf16x4*>(Vn + (size_t)(kb + 1) * 64 + db);
        bf16x4 N2 = *reinterpret_cast<const bf16x4*>(Vn + (size_t)(kb + 2) * 64 + db);
        bf16x4 N3 = *reinterpret_cast<const bf16x4*>(Vn + (size_t)(kb + 3) * 64 + db);

        bf16x4 pkA[4], pkB[4];
        #pragma unroll
        for (int t = 0; t < 4; ++t) {
            bf16x8 k0 = *reinterpret_cast<const bf16x8*>(&Ks[buf][16 * t + l16][quad * 8]);
            bf16x8 k1 = *reinterpret_cast<const bf16x8*>(&Ks[buf][16 * t + l16][32 + quad * 8]);
            f32x4 sA = {}, sB = {};
            sA = __builtin_amdgcn_mfma_f32_16x16x32_bf16(k0, qfA0, sA, 0, 0, 0);
            sA = __builtin_amdgcn_mfma_f32_16x16x32_bf16(k1, qfA1, sA, 0, 0, 0);
            sB = __builtin_amdgcn_mfma_f32_16x16x32_bf16(k0, qfB0, sB, 0, 0, 0);
            sB = __builtin_amdgcn_mfma_f32_16x16x32_bf16(k1, qfB1, sB, 0, 0, 0);
            float a0 = __builtin_amdgcn_exp2f(sA[0]);
            float a1 = __builtin_amdgcn_exp2f(sA[1]);
            float a2 = __builtin_amdgcn_exp2f(sA[2]);
            float a3 = __builtin_amdgcn_exp2f(sA[3]);
            float b0 = __builtin_amdgcn_exp2f(sB[0]);
            float b1 = __builtin_amdgcn_exp2f(sB[1]);
            float b2 = __builtin_amdgcn_exp2f(sB[2]);
            float b3 = __builtin_amdgcn_exp2f(sB[3]);
            lA += (a0 + a1) + (a2 + a3);
            lB += (b0 + b1) + (b2 + b3);
            unsigned* pa = reinterpret_cast<unsigned*>(&pkA[t]);
            pa[0] = pack_bf16(a0, a1); pa[1] = pack_bf16(a2, a3);
            unsigned* pb = reinterpret_cast<unsigned*>(&pkB[t]);
            pb[0] = pack_bf16(b0, b1); pb[1] = pack_bf16(b2, b3);
        }

        #pragma unroll
        for (int t = 0; t < 4; ++t) {
            #pragma unroll
            for (int dt = 0; dt < 4; ++dt) {
                bf16x4 vf = *reinterpret_cast<const bf16x4*>(
                    &Vt[buf][dt * 16 + l16][t * 16 + quad * 4]);
                oA[dt] = __builtin_amdgcn_mfma_f32_16x16x16bf16_1k(vf, pkA[t], oA[dt], 0, 0, 0);
                oB[dt] = __builtin_amdgcn_mfma_f32_16x16x16bf16_1k(vf, pkB[t], oB[dt], 0, 0, 0);
            }
        }

        *reinterpret_cast<bf16x8*>(&Ks[buf ^ 1][krow][kcol]) = nk0;
        *reinterpret_cast<bf16x8*>(&Ks[buf ^ 1][krow][kcol + 8]) = nk1;
        #pragma unroll
        for (int j = 0; j < 4; ++j) {
            bf16x4 w; w[0] = N0[j]; w[1] = N1[j]; w[2] = N2[j]; w[3] = N3[j];
            *reinterpret_cast<bf16x4*>(&Vt[buf ^ 1][db + j][kb]) = w;
        }
        __syncthreads();
        buf ^= 1;
    }

    // ---- tail 1: j0 = Q0. Strip A diagonal (t<=wave), strip B full. ----
    {
        // prefetch tile Q0+64 for tail 2 (Q0+64 <= 1984, always valid)
        const bf16* Kn = Kb + (size_t)(Q0 + 64) * 64;
        const bf16* Vn = Vb + (size_t)(Q0 + 64) * 64;
        bf16x8 nk0 = *reinterpret_cast<const bf16x8*>(Kn + (size_t)krow * 64 + kcol);
        bf16x8 nk1 = *reinterpret_cast<const bf16x8*>(Kn + (size_t)krow * 64 + kcol + 8);
        bf16x4 N0 = *reinterpret_cast<const bf16x4*>(Vn + (size_t)(kb + 0) * 64 + db);
        bf16x4 N1 = *reinterpret_cast<const bf16x4*>(Vn + (size_t)(kb + 1) * 64 + db);
        bf16x4 N2 = *reinterpret_cast<const bf16x4*>(Vn + (size_t)(kb + 2) * 64 + db);
        bf16x4 N3 = *reinterpret_cast<const bf16x4*>(Vn + (size_t)(kb + 3) * 64 + db);

        bf16x4 pkA[4], pkB[4];
        #pragma unroll
        for (int t = 0; t < 4; ++t) {
            bf16x8 k0 = *reinterpret_cast<const bf16x8*>(&Ks[buf][16 * t + l16][quad * 8]);
            bf16x8 k1 = *reinterpret_cast<const bf16x8*>(&Ks[buf][16 * t + l16][32 + quad * 8]);
            f32x4 sB = {};
            sB = __builtin_amdgcn_mfma_f32_16x16x32_bf16(k0, qfB0, sB, 0, 0, 0);
            sB = __builtin_amdgcn_mfma_f32_16x16x32_bf16(k1, qfB1, sB, 0, 0, 0);
            float b0 = __builtin_amdgcn_exp2f(sB[0]);
            float b1 = __builtin_amdgcn_exp2f(sB[1]);
            float b2 = __builtin_amdgcn_exp2f(sB[2]);
            float b3 = __builtin_amdgcn_exp2f(sB[3]);
            lB += (b0 + b1) + (b2 + b3);
            unsigned* pb = reinterpret_cast<unsigned*>(&pkB[t]);
            pb[0] = pack_bf16(b0, b1); pb[1] = pack_bf16(b2, b3);
            if (t <= wave) {
                f32x4 sA = {};
                sA = __builtin_amdgcn_mfma_f32_16x16x32_bf16(k0, qfA0, sA, 0, 0, 0);
                sA = __builtin_amdgcn_mfma_f32_16x16x32_bf16(k1, qfA1, sA, 0, 0, 0);
                if (t == wave) {
                    #pragma unroll
                    for (int r = 0; r < 4; ++r)
                        if (quad * 4 + r > l16) sA[r] = NEG_INF;   // key > qrow
                }
                float a0 = __builtin_amdgcn_exp2f(sA[0]);   // exp2(-inf)=0
                float a1 = __builtin_amdgcn_exp2f(sA[1]);
                float a2 = __builtin_amdgcn_exp2f(sA[2]);
                float a3 = __builtin_amdgcn_exp2f(sA[3]);
                lA += (a0 + a1) + (a2 + a3);
                unsigned* pa = reinterpret_cast<unsigned*>(&pkA[t]);
                pa[0] = pack_bf16(a0, a1); pa[1] = pack_bf16(a2, a3);
            }
        }
        #pragma unroll
        for (int t = 0; t < 4; ++t) {
            #pragma unroll
            for (int dt = 0; dt < 4; ++dt) {
                bf16x4 vf = *reinterpret_cast<const bf16x4*>(
                    &Vt[buf][dt * 16 + l16][t * 16 + quad * 4]);
                oB[dt] = __builtin_amdgcn_mfma_f32_16x16x16bf16_1k(vf, pkB[t], oB[dt], 0, 0, 0);
                if (t <= wave)
                    oA[dt] = __builtin_amdgcn_mfma_f32_16x16x16bf16_1k(vf, pkA[t], oA[dt], 0, 0, 0);
            }
        }

        *reinterpret_cast<bf16x8*>(&Ks[buf ^ 1][krow][kcol]) = nk0;
        *reinterpret_cast<bf16x8*>(&Ks[buf ^ 1][krow][kcol + 8]) = nk1;
        #pragma unroll
        for (int j = 0; j < 4; ++j) {
            bf16x4 w; w[0] = N0[j]; w[1] = N1[j]; w[2] = N2[j]; w[3] = N3[j];
            *reinterpret_cast<bf16x4*>(&Vt[buf ^ 1][db + j][kb]) = w;
        }
        __syncthreads();
        buf ^= 1;
    }

    // ---- tail 2: j0 = Q0+64. Strip B diagonal only. ----
    {
        bf16x4 pkB[4];
        #pragma unroll
        for (int t = 0; t < 4; ++t) {
            if (t <= wave) {
                bf16x8 k0 = *reinterpret_cast<const bf16x8*>(&Ks[buf][16 * t + l16][quad * 8]);
                bf16x8 k1 = *reinterpret_cast<const bf16x8*>(&Ks[buf][16 * t + l16][32 + quad * 8]);
                f32x4 sB = {};
                sB = __builtin_amdgcn_mfma_f32_16x16x32_bf16(k0, qfB0, sB, 0, 0, 0);
                sB = __builtin_amdgcn_mfma_f32_16x16x32_bf16(k1, qfB1, sB, 0, 0, 0);
                if (t == wave) {
                    #pragma unroll
                    for (int r = 0; r < 4; ++r)
                        if (quad * 4 + r > l16) sB[r] = NEG_INF;
                }
                float b0 = __builtin_amdgcn_exp2f(sB[0]);
                float b1 = __builtin_amdgcn_exp2f(sB[1]);
                float b2 = __builtin_amdgcn_exp2f(sB[2]);
                float b3 = __builtin_amdgcn_exp2f(sB[3]);
                lB += (b0 + b1) + (b2 + b3);
                unsigned* pb = reinterpret_cast<unsigned*>(&pkB[t]);
                pb[0] = pack_bf16(b0, b1); pb[1] = pack_bf16(b2, b3);
            }
        }
        #pragma unroll
        for (int t = 0; t < 4; ++t) {
            if (t <= wave) {
                #pragma unroll
                for (int dt = 0; dt < 4; ++dt) {
                    bf16x4 vf = *reinterpret_cast<const bf16x4*>(
                        &Vt[buf][dt * 16 + l16][t * 16 + quad * 4]);
                    oB[dt] = __builtin_amdgcn_mfma_f32_16x16x16bf16_1k(vf, pkB[t], oB[dt], 0, 0, 0);
                }
            }
        }
    }

    // ---- reduce l across quads, normalize, store both strips ----
    lA += __shfl_xor(lA, 16, 64);
    lA += __shfl_xor(lA, 32, 64);
    lB += __shfl_xor(lB, 16, 64);
    lB += __shfl_xor(lB, 32, 64);
    const float invA = 1.f / lA;
    const float invB = 1.f / lB;

    const int b = bh >> 4, h = bh & 15;
    bf16* orowA = O + ((size_t)b * 2048 + qrowA) * 1024 + h * 64;
    bf16* orowB = O + ((size_t)b * 2048 + qrowB) * 1024 + h * 64;
    #pragma unroll
    for (int dt = 0; dt < 4; ++dt) {
        bf16x4 wA, wB;
        unsigned* ua = reinterpret_cast<unsigned*>(&wA);
        ua[0] = pack_bf16(oA[dt][0] * invA, oA[dt][1] * invA);
        ua[1] = pack_bf16(oA[dt][2] * invA, oA[dt][3] * invA);
        *reinterpret_cast<bf16x4*>(orowA + dt * 16 + quad * 4) = wA;
        unsigned* ub = reinterpret_cast<unsigned*>(&wB);
        ub[0] = pack_bf16(oB[dt][0] * invB, oB[dt][1] * invB);
        ub[1] = pack_bf16(oB[dt][2] * invB, oB[dt][3] * invB);
        *reinterpret_cast<bf16x4*>(orowB + dt * 16 + quad * 4) = wB;
    }
}

extern "C" void kernel_launch(void* const* d_in, const int* in_sizes, int n_in,
                              void* d_out, int out_size, void* d_ws, size_t ws_size,
                              hipStream_t stream) {
    const float* x    = (const float*)d_in[0];
    // d_in[1] = mask (int32 tril) — causal is hardcoded
    const float* Wqkv = (const float*)d_in[2];
    const float* Wout = (const float*)d_in[3];
    float* out = (float*)d_out;

    char* ws = (char*)d_ws;
    bf16* x_bf    = (bf16*)(ws);                  //  8 MB  [4096,1024]
    bf16* wqkv_bf = (bf16*)(ws + 8388608);        //  6 MB  [3072,1024]
    bf16* wout_bf = (bf16*)(ws + 14680064);       //  2 MB  [1024,1024]
    bf16* q       = (bf16*)(ws + 16777216);       //  8 MB  [32,2048,64] (pre-scaled)
    bf16* k       = (bf16*)(ws + 25165824);       //  8 MB
    bf16* v       = (bf16*)(ws + 33554432);       //  8 MB
    bf16* ao      = (bf16*)(ws + 41943040);       //  8 MB  [4096,1024]

    cast_all<<<8192, 256, 0, stream>>>(x, Wqkv, Wout, x_bf, wqkv_bf, wout_bf);
    gemm256_qkv<<<dim3(16, 12), 512, 0, stream>>>(x_bf, wqkv_bf, q, k, v);
    flash_attn<<<dim3(32, 16), 256, 0, stream>>>(q, k, v, ao);
    gemm128<1><<<dim3(32, 8), 256, 0, stream>>>(ao, wout_bf, out, nullptr, nullptr, nullptr, 1024, 1024);
}

// Round 2
// 185.792 us; speedup vs baseline: 1.0159x; 1.0159x over previous
//
#include <hip/hip_runtime.h>
#include <hip/hip_bf16.h>

// Causal MHA: B=2 N=2048 D=1024 H=16 DH=64. fp32 in/out, bf16 MFMA internal.
// R10 = R9 with the gemm256_qkv LDS swizzle extended from 2 bits to 3 bits:
// byte-offset XOR {8,9,10}->{4,5,6}. R9's 2-bit version left bank bit 4
// constant per 16-lane quarter-wave -> 4 accesses/bank vs 2 free -> measured
// exactly +4 conflict cycles per ds_read_b128 (2.36M total). 3-bit version
// spreads each quarter-wave over 8 distinct 16B slots (2 lanes each) = free.
// Staging source pre-swizzle updated to match (chunk XOR {4,5,6}->{0,1,2}).
// Everything else unchanged from R9.

typedef __hip_bfloat16 bf16;
typedef short bf16x8 __attribute__((ext_vector_type(8)));   // 4 VGPR (K=32 MFMA A/B)
typedef short bf16x4 __attribute__((ext_vector_type(4)));   // 2 VGPR (K=16 MFMA A/B)
typedef float f32x4 __attribute__((ext_vector_type(4)));    // MFMA C/D frag

#define QSCALE 0.1803368801111204f   // 0.125 * log2(e): S in log2 domain

typedef __attribute__((address_space(3))) unsigned int lds_u32;
typedef const __attribute__((address_space(1))) unsigned int glob_u32;

__device__ __forceinline__ void glds16(const void* g, void* l) {
    __builtin_amdgcn_global_load_lds((glob_u32*)g, (lds_u32*)l, 16, 0, 0);
}

__device__ __forceinline__ short f2bf(float f) {
    __hip_bfloat16 h = __float2bfloat16(f);
    return *reinterpret_cast<short*>(&h);
}

// pack two f32 -> two bf16 (round-to-nearest-up) in one u32: {hi16(b), hi16(a)}
__device__ __forceinline__ unsigned pack_bf16(float a, float b) {
    unsigned au = __builtin_bit_cast(unsigned, a) + 0x8000u;
    unsigned bu = __builtin_bit_cast(unsigned, b) + 0x8000u;
    return __builtin_amdgcn_perm(bu, au, 0x07060302u);  // bytes: b[3],b[2],a[3],a[2]
}

// ---------------- fused cast fp32 -> bf16 for x, W_qkv, W_out ----------------
// ranges are 256-thread-block aligned: no intra-block divergence.
__global__ void cast_all(const float* __restrict__ x, const float* __restrict__ wqkv,
                         const float* __restrict__ wout,
                         bf16* __restrict__ xb, bf16* __restrict__ wqkvb,
                         bf16* __restrict__ woutb) {
    int i = blockIdx.x * blockDim.x + threadIdx.x;   // 0 .. 2097151 (x4 elems)
    const float4* s; short4* d; int o;
    if (i < 1048576)               { s = (const float4*)x;    d = (short4*)xb;    o = i; }
    else if (i < 1835008)          { s = (const float4*)wqkv; d = (short4*)wqkvb; o = i - 1048576; }
    else                           { s = (const float4*)wout; d = (short4*)woutb; o = i - 1835008; }
    float4 f = s[o];
    short4 v;
    v.x = f2bf(f.x); v.y = f2bf(f.y); v.z = f2bf(f.z); v.w = f2bf(f.w);
    d[o] = v;
}

// ---------- QKV GEMM, 256x256 tile, 8-phase counted-vmcnt schedule ----------
// C[4096,3072] = A[4096,1024] @ Bt[3072,1024]^T, scattered to q/k/v [32,2048,64].
// 512 threads = 8 waves (wm in {0,1} -> 128 rows, wn in {0..3} -> 64 cols).
// LDS: As/Bs [2 buf][2 half][128][64] bf16 = 64 KiB each. Swizzle: byte offset
// XOR bits {8,9,10} -> {4,5,6} (involution; applied on ds_read addr AND
// pre-applied to the per-lane global source chunk so global_load_lds's linear
// dest lands swizzled). Per 16-lane quarter-wave this spreads frag reads over
// 8 distinct 16B slots (2 lanes/slot) = bank-conflict-free at 256 B/clock.
#define MMAC(mh, nh) do {                                                          \
    _Pragma("unroll")                                                              \
    for (int mt = 0; mt < 4; ++mt) {                                               \
        _Pragma("unroll")                                                          \
        for (int j = 0; j < 2; ++j) {                                              \
            f32x4 c = acc[(mh)*4+mt][(nh)*2+j];                                    \
            c = __builtin_amdgcn_mfma_f32_16x16x32_bf16(af[mt][0], bfr[nh][j][0], c, 0, 0, 0); \
            c = __builtin_amdgcn_mfma_f32_16x16x32_bf16(af[mt][1], bfr[nh][j][1], c, 0, 0, 0); \
            acc[(mh)*4+mt][(nh)*2+j] = c;                                          \
        }                                                                          \
    }                                                                              \
} while (0)

__global__ __launch_bounds__(512, 2)
void gemm256_qkv(const bf16* __restrict__ A, const bf16* __restrict__ Bt,
                 bf16* __restrict__ qp, bf16* __restrict__ kp, bf16* __restrict__ vp) {
    constexpr int K = 1024, NT = K / 64;          // 16 K-tiles of 64
    __shared__ alignas(16) short As[2 * 16384];   // [buf][half][128][64], 64 KiB
    __shared__ alignas(16) short Bs[2 * 16384];   // 64 KiB

    const int tid  = threadIdx.x;
    const int lane = tid & 63;
    const int wave = tid >> 6;
    const int quad = lane >> 4, l16 = lane & 15;
    const int wm = wave >> 2;        // 0..1: row half
    const int wn = wave & 3;         // 0..3: 64-col strip
    const int hb = wn >> 1;          // B half this wave reads
    const int m0 = blockIdx.x * 256;
    const int n0 = blockIdx.y * 256;

    // staging: thread t's linear 16B dest chunk is t (byte t*16) in its half;
    // pre-apply the (self-inverse) swizzle to the SOURCE chunk index:
    // chunk XOR {4,5,6}->{0,1,2}  ==  byte XOR {8,9,10}->{4,5,6}.
    const int ts    = tid ^ ((tid >> 4) & 1) ^ (((tid >> 5) & 1) << 1) ^ (((tid >> 6) & 1) << 2);
    const int tsrow = ts >> 3;           // 0..63
    const int tscol = (ts & 7) * 8;      // elems

    const bf16* Ag = A  + (size_t)(m0 + tsrow) * K + tscol;
    const bf16* Bg = Bt + (size_t)(n0 + tsrow) * K + tscol;
    short* Asl = As + tid * 8;
    short* Bsl = Bs + tid * 8;

    auto stageA = [&](int T, int h) {   // half h (128 rows) of A K-tile T -> buf T&1
        short* d = Asl + (T & 1) * 16384 + h * 8192;
        const bf16* g = Ag + (size_t)(h * 128) * K + T * 64;
        glds16(g, d);
        glds16(g + (size_t)64 * K, d + 4096);
    };
    auto stageB = [&](int T, int h) {
        short* d = Bsl + (T & 1) * 16384 + h * 8192;
        const bf16* g = Bg + (size_t)(h * 128) * K + T * 64;
        glds16(g, d);
        glds16(g + (size_t)64 * K, d + 4096);
    };

    bf16x8 af[4][2];        // A frags: 4 m-frags x 2 k-steps (current mh)
    bf16x8 bfr[2][2][2];    // B frags: [nh][j][ks] - both nh halves kept live
    f32x4  acc[8][4] = {};  // per-wave C: 128 rows x 64 cols

    auto rdA = [&](const char* ab, int mh) {
        #pragma unroll
        for (int mt = 0; mt < 4; ++mt) {
            const int lr = mh * 64 + mt * 16 + l16;
            #pragma unroll
            for (int ks = 0; ks < 2; ++ks) {
                int o = lr * 128 + ks * 64 + quad * 16;
                o ^= (((o >> 8) & 1) << 4) ^ (((o >> 9) & 1) << 5) ^ (((o >> 10) & 1) << 6);
                af[mt][ks] = *reinterpret_cast<const bf16x8*>(ab + o);
            }
        }
    };
    auto rdB = [&](const char* bb, int nh) {
        #pragma unroll
        for (int j = 0; j < 2; ++j) {
            const int lr = (wn & 1) * 64 + (nh * 2 + j) * 16 + l16;
            #pragma unroll
            for (int ks = 0; ks < 2; ++ks) {
                int o = lr * 128 + ks * 64 + quad * 16;
                o ^= (((o >> 8) & 1) << 4) ^ (((o >> 9) & 1) << 5) ^ (((o >> 10) & 1) << 6);
                bfr[nh][j][ks] = *reinterpret_cast<const bf16x8*>(bb + o);
            }
        }
    };

    // prologue: tile0 fully + tile1 {B0, A0}. Newest 4 loads = tile1's.
    stageA(0, 0); stageA(0, 1); stageB(0, 0); stageB(0, 1);
    stageB(1, 0); stageA(1, 0);
    asm volatile("s_waitcnt vmcnt(4)" ::: "memory");
    __builtin_amdgcn_s_barrier();

    for (int T = 0; T < NT; ++T) {
        const char* ab = (const char*)As + (T & 1) * 32768 + wm * 16384;
        const char* bb = (const char*)Bs + (T & 1) * 32768 + hb * 16384;
        const bool st1 = (T + 1 < NT), st2 = (T + 2 < NT);

        // ---- phase 0: quadrant (mh0, nh0); stage B1(T+1) ----
        rdA(ab, 0);
        rdB(bb, 0);
        if (st1) stageB(T + 1, 1);
        __builtin_amdgcn_s_barrier();
        asm volatile("s_waitcnt lgkmcnt(0)" ::: "memory");
        __builtin_amdgcn_sched_barrier(0);
        __builtin_amdgcn_s_setprio(1);
        MMAC(0, 0);
        __builtin_amdgcn_s_setprio(0);
        __builtin_amdgcn_s_barrier();

        // ---- phase 1: quadrant (mh0, nh1); stage A1(T+1) ----
        rdB(bb, 1);
        if (st1) stageA(T + 1, 1);
        __builtin_amdgcn_s_barrier();
        asm volatile("s_waitcnt lgkmcnt(0)" ::: "memory");
        __builtin_amdgcn_sched_barrier(0);
        __builtin_amdgcn_s_setprio(1);
        MMAC(0, 1);
        __builtin_amdgcn_s_setprio(0);
        __builtin_amdgcn_s_barrier();

        // ---- phase 2: quadrant (mh1, nh1); stage B0(T+2) ----
        rdA(ab, 1);
        if (st2) stageB(T + 2, 0);
        __builtin_amdgcn_s_barrier();
        asm volatile("s_waitcnt lgkmcnt(0)" ::: "memory");
        __builtin_amdgcn_sched_barrier(0);
        __builtin_amdgcn_s_setprio(1);
        MMAC(1, 1);
        __builtin_amdgcn_s_setprio(0);
        __builtin_amdgcn_s_barrier();

        // ---- phase 3: quadrant (mh1, nh0) (frags already live); stage A0(T+2);
        //      counted vmcnt at the tile boundary (never 0 until the tail). ----
        if (st2) stageA(T + 2, 0);
        __builtin_amdgcn_s_setprio(1);
        MMAC(1, 0);
        __builtin_amdgcn_s_setprio(0);
        if (st1) {
            if (st2) asm volatile("s_waitcnt vmcnt(4)" ::: "memory");
            else     asm volatile("s_waitcnt vmcnt(0)" ::: "memory");
            __builtin_amdgcn_s_barrier();
        }
    }

    // ---- epilogue: scatter to q/k/v [b,h,n,dh]; sel uniform per block ----
    const int sel  = n0 >> 10;                  // 0=q, 1=k, 2=v
    const int remb = n0 & 1023;
    bf16* dst = (sel == 0) ? qp : ((sel == 1) ? kp : vp);
    const float scale = (sel == 0) ? QSCALE : 1.0f;
    #pragma unroll
    for (int mt = 0; mt < 8; ++mt) {
        #pragma unroll
        for (int nt = 0; nt < 4; ++nt) {
            #pragma unroll
            for (int r = 0; r < 4; ++r) {
                int gm  = m0 + wm * 128 + mt * 16 + quad * 4 + r;
                int rem = remb + wn * 64 + nt * 16 + l16;
                int h = rem >> 6, dh = rem & 63;
                int b = gm >> 11, nq = gm & 2047;
                dst[((((size_t)b * 16 + h) * 2048) + nq) * 64 + dh] =
                    __float2bfloat16(acc[mt][nt][r] * scale);
            }
        }
    }
}

// ---------- GEMM 128x128: C[M,Nc] = A[M,K] @ Bt[Nc,K]^T (both K-major) -------
// (unchanged; used for the output projection only)
template<int EPI>
__global__ __launch_bounds__(256)
void gemm128(const bf16* __restrict__ A, const bf16* __restrict__ Bt,
             float* __restrict__ Cf,
             bf16* __restrict__ qp, bf16* __restrict__ kp, bf16* __restrict__ vp,
             int K, int Ncols) {
    __shared__ alignas(16) short As[2][4096];   // 8 KB/buf
    __shared__ alignas(16) short Bs[2][4096];

    const int tid = threadIdx.x;
    const int wave = tid >> 6, lane = tid & 63;
    const int quad = lane >> 4, l16 = lane & 15;
    const int wm = wave >> 1, wn = wave & 1;
    const int m0 = blockIdx.x * 128;
    const int n0 = blockIdx.y * 128;

    f32x4 acc[4][4] = {};

    const int srow = tid >> 2;
    const int skk  = (((tid & 3) ^ ((tid >> 3) & 3))) * 8;
    const bf16* Ag = A  + (size_t)(m0 + srow) * K + skk;
    const bf16* Bg = Bt + (size_t)(n0 + srow) * K + skk;
    const size_t rowskip = (size_t)64 * K;
    short* Asl = &As[0][0] + tid * 8;
    short* Bsl = &Bs[0][0] + tid * 8;

    const int xk = (quad ^ ((l16 >> 1) & 3)) * 8;
    const int arow = wm * 64 + l16;
    const int brow = wn * 64 + l16;

    const int KI = K >> 5;
    glds16(Ag, Asl);
    glds16(Ag + rowskip, Asl + 2048);
    glds16(Bg, Bsl);
    glds16(Bg + rowskip, Bsl + 2048);
    __syncthreads();

    int buf = 0;
    for (int ki = 0; ki < KI; ++ki) {
        if (ki + 1 < KI) {
            const bf16* ag = Ag + (ki + 1) * 32;
            const bf16* bg = Bg + (ki + 1) * 32;
            short* ad = Asl + (buf ^ 1) * 4096;
            short* bd = Bsl + (buf ^ 1) * 4096;
            glds16(ag, ad);
            glds16(ag + rowskip, ad + 2048);
            glds16(bg, bd);
            glds16(bg + rowskip, bd + 2048);
        }
        const short* ab = &As[buf][0];
        const short* bb = &Bs[buf][0];
        bf16x8 af[4], bf[4];
        #pragma unroll
        for (int mt = 0; mt < 4; ++mt)
            af[mt] = *reinterpret_cast<const bf16x8*>(ab + (arow + mt * 16) * 32 + xk);
        #pragma unroll
        for (int nt = 0; nt < 4; ++nt)
            bf[nt] = *reinterpret_cast<const bf16x8*>(bb + (brow + nt * 16) * 32 + xk);
        #pragma unroll
        for (int mt = 0; mt < 4; ++mt)
            #pragma unroll
            for (int nt = 0; nt < 4; ++nt)
                acc[mt][nt] = __builtin_amdgcn_mfma_f32_16x16x32_bf16(
                    af[mt], bf[nt], acc[mt][nt], 0, 0, 0);
        __syncthreads();
        buf ^= 1;
    }

    #pragma unroll
    for (int mt = 0; mt < 4; ++mt) {
        #pragma unroll
        for (int nt = 0; nt < 4; ++nt) {
            #pragma unroll
            for (int r = 0; r < 4; ++r) {
                int gm = m0 + wm * 64 + mt * 16 + quad * 4 + r;
                int gn = n0 + wn * 64 + nt * 16 + l16;
                float val = acc[mt][nt][r];
                if (EPI == 0) {
                    int sel = gn >> 10, rem = gn & 1023;
                    int h = rem >> 6, dh = rem & 63;
                    int b = gm >> 11, nq = gm & 2047;
                    if (sel == 0) val *= QSCALE;
                    bf16* dst = (sel == 0) ? qp : ((sel == 1) ? kp : vp);
                    dst[((((size_t)b * 16 + h) * 2048) + nq) * 64 + dh] = __float2bfloat16(val);
                } else {
                    Cf[(size_t)gm * Ncols + gn] = val;
                }
            }
        }
    }
}

// ---------------- flash attention (causal), S^T form, 128-row q-tiles --------
// (unchanged from R8)
__global__ __launch_bounds__(256)
void flash_attn(const bf16* __restrict__ Q, const bf16* __restrict__ K,
                const bf16* __restrict__ V, bf16* __restrict__ O) {
    __shared__ alignas(16) short Ks[2][64][72];   // [buf][key][dh], +8 pad
    __shared__ alignas(16) short Vt[2][64][68];   // [buf][dh][key]

    const int tid = threadIdx.x;
    const int wave = tid >> 6, lane = tid & 63;
    const int quad = lane >> 4, l16 = lane & 15;
    const int bh = blockIdx.x;
    const int yy = blockIdx.y;
    const int qt = (yy < 8) ? yy : (15 - (yy & 7));   // pair y,y+8 -> 34 iters/CU
    const int Q0 = qt * 128;
    const float NEG_INF = -__builtin_inff();

    const bf16* Qb = Q + (size_t)bh * 2048 * 64;
    const bf16* Kb = K + (size_t)bh * 2048 * 64;
    const bf16* Vb = V + (size_t)bh * 2048 * 64;

    // Q B-frags for both strips
    const int qrowA = Q0 + wave * 16 + l16;
    const int qrowB = qrowA + 64;
    const bf16x8 qfA0 = *reinterpret_cast<const bf16x8*>(Qb + (size_t)qrowA * 64 + quad * 8);
    const bf16x8 qfA1 = *reinterpret_cast<const bf16x8*>(Qb + (size_t)qrowA * 64 + 32 + quad * 8);
    const bf16x8 qfB0 = *reinterpret_cast<const bf16x8*>(Qb + (size_t)qrowB * 64 + quad * 8);
    const bf16x8 qfB1 = *reinterpret_cast<const bf16x8*>(Qb + (size_t)qrowB * 64 + 32 + quad * 8);

    float lA = 0.f, lB = 0.f;
    f32x4 oA[4] = {}, oB[4] = {};

    const int krow = tid >> 2;
    const int kcol = (tid & 3) * 16;
    const int kb = (tid & 15) * 4;
    const int db = (tid >> 4) * 4;

    {   // prologue: stage K/V tile j0=0 into buf 0
        bf16x8 a0 = *reinterpret_cast<const bf16x8*>(Kb + (size_t)krow * 64 + kcol);
        bf16x8 a1 = *reinterpret_cast<const bf16x8*>(Kb + (size_t)krow * 64 + kcol + 8);
        bf16x4 L0 = *reinterpret_cast<const bf16x4*>(Vb + (size_t)(kb + 0) * 64 + db);
        bf16x4 L1 = *reinterpret_cast<const bf16x4*>(Vb + (size_t)(kb + 1) * 64 + db);
        bf16x4 L2 = *reinterpret_cast<const bf16x4*>(Vb + (size_t)(kb + 2) * 64 + db);
        bf16x4 L3 = *reinterpret_cast<const bf16x4*>(Vb + (size_t)(kb + 3) * 64 + db);
        *reinterpret_cast<bf16x8*>(&Ks[0][krow][kcol]) = a0;
        *reinterpret_cast<bf16x8*>(&Ks[0][krow][kcol + 8]) = a1;
        #pragma unroll
        for (int j = 0; j < 4; ++j) {
            bf16x4 w; w[0] = L0[j]; w[1] = L1[j]; w[2] = L2[j]; w[3] = L3[j];
            *reinterpret_cast<bf16x4*>(&Vt[0][db + j][kb]) = w;
        }
    }
    __syncthreads();

    int buf = 0;
    // ---- main loop: j0 < Q0, both strips full ----
    for (int j0 = 0; j0 < Q0; j0 += 64) {
        const bf16* Kn = Kb + (size_t)(j0 + 64) * 64;
        const bf16* Vn = Vb + (size_t)(j0 + 64) * 64;
        bf16x8 nk0 = *reinterpret_cast<const bf16x8*>(Kn + (size_t)krow * 64 + kcol);
        bf16x8 nk1 = *reinterpret_cast<const bf16x8*>(Kn + (size_t)krow * 64 + kcol + 8);
        bf16x4 N0 = *reinterpret_cast<const bf16x4*>(Vn + (size_t)(kb + 0) * 64 + db);
        bf16x4 N1 = *reinterpret_cast<const bf16x4*>(Vn + (size_t)(kb + 1) * 64 + db);
        bf16x4 N2 = *reinterpret_cast<const bf16x4*>(Vn + (size_t)(kb + 2) * 64 + db);
        bf16x4 N3 = *reinterpret_cast<const bf16x4*>(Vn + (size_t)(kb + 3) * 64 + db);

        bf16x4 pkA[4], pkB[4];
        #pragma unroll
        for (int t = 0; t < 4; ++t) {
            bf16x8 k0 = *reinterpret_cast<const bf16x8*>(&Ks[buf][16 * t + l16][quad * 8]);
            bf16x8 k1 = *reinterpret_cast<const bf16x8*>(&Ks[buf][16 * t + l16][32 + quad * 8]);
            f32x4 sA = {}, sB = {};
            sA = __builtin_amdgcn_mfma_f32_16x16x32_bf16(k0, qfA0, sA, 0, 0, 0);
            sA = __builtin_amdgcn_mfma_f32_16x16x32_bf16(k1, qfA1, sA, 0, 0, 0);
            sB = __builtin_amdgcn_mfma_f32_16x16x32_bf16(k0, qfB0, sB, 0, 0, 0);
            sB = __builtin_amdgcn_mfma_f32_16x16x32_bf16(k1, qfB1, sB, 0, 0, 0);
            float a0 = __builtin_amdgcn_exp2f(sA[0]);
            float a1 = __builtin_amdgcn_exp2f(sA[1]);
            float a2 = __builtin_amdgcn_exp2f(sA[2]);
            float a3 = __builtin_amdgcn_exp2f(sA[3]);
            float b0 = __builtin_amdgcn_exp2f(sB[0]);
            float b1 = __builtin_amdgcn_exp2f(sB[1]);
            float b2 = __builtin_amdgcn_exp2f(sB[2]);
            float b3 = __builtin_amdgcn_exp2f(sB[3]);
            lA += (a0 + a1) + (a2 + a3);
            lB += (b0 + b1) + (b2 + b3);
            unsigned* pa = reinterpret_cast<unsigned*>(&pkA[t]);
            pa[0] = pack_bf16(a0, a1); pa[1] = pack_bf16(a2, a3);
            unsigned* pb = reinterpret_cast<unsigned*>(&pkB[t]);
            pb[0] = pack_bf16(b0, b1); pb[1] = pack_bf16(b2, b3);
        }

        #pragma unroll
        for (int t = 0; t < 4; ++t) {
            #pragma unroll
            for (int dt = 0; dt < 4; ++dt) {
                bf16x4 vf = *reinterpret_cast<const bf16x4*>(
                    &Vt[buf][dt * 16 + l16][t * 16 + quad * 4]);
                oA[dt] = __builtin_amdgcn_mfma_f32_16x16x16bf16_1k(vf, pkA[t], oA[dt], 0, 0, 0);
                oB[dt] = __builtin_amdgcn_mfma_f32_16x16x16bf16_1k(vf, pkB[t], oB[dt], 0, 0, 0);
            }
        }

        *reinterpret_cast<bf16x8*>(&Ks[buf ^ 1][krow][kcol]) = nk0;
        *reinterpret_cast<bf16x8*>(&Ks[buf ^ 1][krow][kcol + 8]) = nk1;
        #pragma unroll
        for (int j = 0; j < 4; ++j) {
            bf16x4 w; w[0] = N0[j]; w[1] = N1[j]; w[2] = N2[j]; w[3] = N3[j];
            *reinterpret_cast<bf16x4*>(&Vt[buf ^ 1][db + j][kb]) = w;
        }
        __syncthreads();
        buf ^= 1;
    }

    // ---- tail 1: j0 = Q0. Strip A diagonal (t<=wave), strip B full. ----
    {
        // prefetch tile Q0+64 for tail 2 (Q0+64 <= 1984, always valid)
        const bf16* Kn = Kb + (size_t)(Q0 + 64) * 64;
        const bf16* Vn = Vb + (size_t)(Q0 + 64) * 64;
        bf16x8 nk0 = *reinterpret_cast<const bf16x8*>(Kn + (size_t)krow * 64 + kcol);
        bf16x8 nk1 = *reinterpret_cast<const bf16x8*>(Kn + (size_t)krow * 64 + kcol + 8);
        bf16x4 N0 = *reinterpret_cast<const bf16x4*>(Vn + (size_t)(kb + 0) * 64 + db);
        bf16x4 N1 = *reinterpret_cast<const bf16x4*>(Vn + (size_t)(kb + 1) * 64 + db);
        bf16x4 N2 = *reinterpret_cast<const bf16x4*>(Vn + (size_t)(kb + 2) * 64 + db);
        bf16x4 N3 = *reinterpret_cast<const bf16x4*>(Vn + (size_t)(kb + 3) * 64 + db);

        bf16x4 pkA[4], pkB[4];
        #pragma unroll
        for (int t = 0; t < 4; ++t) {
            bf16x8 k0 = *reinterpret_cast<const bf16x8*>(&Ks[buf][16 * t + l16][quad * 8]);
            bf16x8 k1 = *reinterpret_cast<const bf16x8*>(&Ks[buf][16 * t + l16][32 + quad * 8]);
            f32x4 sB = {};
            sB = __builtin_amdgcn_mfma_f32_16x16x32_bf16(k0, qfB0, sB, 0, 0, 0);
            sB = __builtin_amdgcn_mfma_f32_16x16x32_bf16(k1, qfB1, sB, 0, 0, 0);
            float b0 = __builtin_amdgcn_exp2f(sB[0]);
            float b1 = __builtin_amdgcn_exp2f(sB[1]);
            float b2 = __builtin_amdgcn_exp2f(sB[2]);
            float b3 = __builtin_amdgcn_exp2f(sB[3]);
            lB += (b0 + b1) + (b2 + b3);
            unsigned* pb = reinterpret_cast<unsigned*>(&pkB[t]);
            pb[0] = pack_bf16(b0, b1); pb[1] = pack_bf16(b2, b3);
            if (t <= wave) {
                f32x4 sA = {};
                sA = __builtin_amdgcn_mfma_f32_16x16x32_bf16(k0, qfA0, sA, 0, 0, 0);
                sA = __builtin_amdgcn_mfma_f32_16x16x32_bf16(k1, qfA1, sA, 0, 0, 0);
                if (t == wave) {
                    #pragma unroll
                    for (int r = 0; r < 4; ++r)
                        if (quad * 4 + r > l16) sA[r] = NEG_INF;   // key > qrow
                }
                float a0 = __builtin_amdgcn_exp2f(sA[0]);   // exp2(-inf)=0
                float a1 = __builtin_amdgcn_exp2f(sA[1]);
                float a2 = __builtin_amdgcn_exp2f(sA[2]);
                float a3 = __builtin_amdgcn_exp2f(sA[3]);
                lA += (a0 + a1) + (a2 + a3);
                unsigned* pa = reinterpret_cast<unsigned*>(&pkA[t]);
                pa[0] = pack_bf16(a0, a1); pa[1] = pack_bf16(a2, a3);
            }
        }
        #pragma unroll
        for (int t = 0; t < 4; ++t) {
            #pragma unroll
            for (int dt = 0; dt < 4; ++dt) {
                bf16x4 vf = *reinterpret_cast<const bf16x4*>(
                    &Vt[buf][dt * 16 + l16][t * 16 + quad * 4]);
                oB[dt] = __builtin_amdgcn_mfma_f32_16x16x16bf16_1k(vf, pkB[t], oB[dt], 0, 0, 0);
                if (t <= wave)
                    oA[dt] = __builtin_amdgcn_mfma_f32_16x16x16bf16_1k(vf, pkA[t], oA[dt], 0, 0, 0);
            }
        }

        *reinterpret_cast<bf16x8*>(&Ks[buf ^ 1][krow][kcol]) = nk0;
        *reinterpret_cast<bf16x8*>(&Ks[buf ^ 1][krow][kcol + 8]) = nk1;
        #pragma unroll
        for (int j = 0; j < 4; ++j) {
            bf16x4 w; w[0] = N0[j]; w[1] = N1[j]; w[2] = N2[j]; w[3] = N3[j];
            *reinterpret_cast<bf16x4*>(&Vt[buf ^ 1][db + j][kb]) = w;
        }
        __syncthreads();
        buf ^= 1;
    }

    // ---- tail 2: j0 = Q0+64. Strip B diagonal only. ----
    {
        bf16x4 pkB[4];
        #pragma unroll
        for (int t = 0; t < 4; ++t) {
            if (t <= wave) {
                bf16x8 k0 = *reinterpret_cast<const bf16x8*>(&Ks[buf][16 * t + l16][quad * 8]);
                bf16x8 k1 = *reinterpret_cast<const bf16x8*>(&Ks[buf][16 * t + l16][32 + quad * 8]);
                f32x4 sB = {};
                sB = __builtin_amdgcn_mfma_f32_16x16x32_bf16(k0, qfB0, sB, 0, 0, 0);
                sB = __builtin_amdgcn_mfma_f32_16x16x32_bf16(k1, qfB1, sB, 0, 0, 0);
                if (t == wave) {
                    #pragma unroll
                    for (int r = 0; r < 4; ++r)
                        if (quad * 4 + r > l16) sB[r] = NEG_INF;
                }
                float b0 = __builtin_amdgcn_exp2f(sB[0]);
                float b1 = __builtin_amdgcn_exp2f(sB[1]);
                float b2 = __builtin_amdgcn_exp2f(sB[2]);
                float b3 = __builtin_amdgcn_exp2f(sB[3]);
                lB += (b0 + b1) + (b2 + b3);
                unsigned* pb = reinterpret_cast<unsigned*>(&pkB[t]);
                pb[0] = pack_bf16(b0, b1); pb[1] = pack_bf16(b2, b3);
            }
        }
        #pragma unroll
        for (int t = 0; t < 4; ++t) {
            if (t <= wave) {
                #pragma unroll
                for (int dt = 0; dt < 4; ++dt) {
                    bf16x4 vf = *reinterpret_cast<const bf16x4*>(
                        &Vt[buf][dt * 16 + l16][t * 16 + quad * 4]);
                    oB[dt] = __builtin_amdgcn_mfma_f32_16x16x16bf16_1k(vf, pkB[t], oB[dt], 0, 0, 0);
                }
            }
        }
    }

    // ---- reduce l across quads, normalize, store both strips ----
    lA += __shfl_xor(lA, 16, 64);
    lA += __shfl_xor(lA, 32, 64);
    lB += __shfl_xor(lB, 16, 64);
    lB += __shfl_xor(lB, 32, 64);
    const float invA = 1.f / lA;
    const float invB = 1.f / lB;

    const int b = bh >> 4, h = bh & 15;
    bf16* orowA = O + ((size_t)b * 2048 + qrowA) * 1024 + h * 64;
    bf16* orowB = O + ((size_t)b * 2048 + qrowB) * 1024 + h * 64;
    #pragma unroll
    for (int dt = 0; dt < 4; ++dt) {
        bf16x4 wA, wB;
        unsigned* ua = reinterpret_cast<unsigned*>(&wA);
        ua[0] = pack_bf16(oA[dt][0] * invA, oA[dt][1] * invA);
        ua[1] = pack_bf16(oA[dt][2] * invA, oA[dt][3] * invA);
        *reinterpret_cast<bf16x4*>(orowA + dt * 16 + quad * 4) = wA;
        unsigned* ub = reinterpret_cast<unsigned*>(&wB);
        ub[0] = pack_bf16(oB[dt][0] * invB, oB[dt][1] * invB);
        ub[1] = pack_bf16(oB[dt][2] * invB, oB[dt][3] * invB);
        *reinterpret_cast<bf16x4*>(orowB + dt * 16 + quad * 4) = wB;
    }
}

extern "C" void kernel_launch(void* const* d_in, const int* in_sizes, int n_in,
                              void* d_out, int out_size, void* d_ws, size_t ws_size,
                              hipStream_t stream) {
    const float* x    = (const float*)d_in[0];
    // d_in[1] = mask (int32 tril) — causal is hardcoded
    const float* Wqkv = (const float*)d_in[2];
    const float* Wout = (const float*)d_in[3];
    float* out = (float*)d_out;

    char* ws = (char*)d_ws;
    bf16* x_bf    = (bf16*)(ws);                  //  8 MB  [4096,1024]
    bf16* wqkv_bf = (bf16*)(ws + 8388608);        //  6 MB  [3072,1024]
    bf16* wout_bf = (bf16*)(ws + 14680064);       //  2 MB  [1024,1024]
    bf16* q       = (bf16*)(ws + 16777216);       //  8 MB  [32,2048,64] (pre-scaled)
    bf16* k       = (bf16*)(ws + 25165824);       //  8 MB
    bf16* v       = (bf16*)(ws + 33554432);       //  8 MB
    bf16* ao      = (bf16*)(ws + 41943040);       //  8 MB  [4096,1024]

    cast_all<<<8192, 256, 0, stream>>>(x, Wqkv, Wout, x_bf, wqkv_bf, wout_bf);
    gemm256_qkv<<<dim3(16, 12), 512, 0, stream>>>(x_bf, wqkv_bf, q, k, v);
    flash_attn<<<dim3(32, 16), 256, 0, stream>>>(q, k, v, ao);
    gemm128<1><<<dim3(32, 8), 256, 0, stream>>>(ao, wout_bf, out, nullptr, nullptr, nullptr, 1024, 1024);
}

// Round 3
// 181.286 us; speedup vs baseline: 1.0412x; 1.0249x over previous
//
#include <hip/hip_runtime.h>
#include <hip/hip_bf16.h>

// Causal MHA: B=2 N=2048 D=1024 H=16 DH=64. fp32 in/out, bf16 MFMA internal.
// R11 = R8's kernel set (gemm128 QKV + flash + gemm128 out) + R9's fused
// single-launch cast. The 256x256 8-phase QKV experiment (R9/R10) is dropped:
// even conflict-free it measured ~42 us vs gemm128's ~35 us — at K=1024 the
// 8-phase structure's fixed per-tile costs (8 barriers, phase-sync LDS reads,
// 16 tiles only, 192/256 CUs, 1 block/CU) dominate; gemm128 at 3 blocks/CU
// wins via implicit wave-level overlap (m114 mechanism).

typedef __hip_bfloat16 bf16;
typedef short bf16x8 __attribute__((ext_vector_type(8)));   // 4 VGPR (K=32 MFMA A/B)
typedef short bf16x4 __attribute__((ext_vector_type(4)));   // 2 VGPR (K=16 MFMA A/B)
typedef float f32x4 __attribute__((ext_vector_type(4)));    // MFMA C/D frag

#define QSCALE 0.1803368801111204f   // 0.125 * log2(e): S in log2 domain

typedef __attribute__((address_space(3))) unsigned int lds_u32;
typedef const __attribute__((address_space(1))) unsigned int glob_u32;

__device__ __forceinline__ void glds16(const void* g, void* l) {
    __builtin_amdgcn_global_load_lds((glob_u32*)g, (lds_u32*)l, 16, 0, 0);
}

__device__ __forceinline__ short f2bf(float f) {
    __hip_bfloat16 h = __float2bfloat16(f);
    return *reinterpret_cast<short*>(&h);
}

// pack two f32 -> two bf16 (round-to-nearest-up) in one u32: {hi16(b), hi16(a)}
__device__ __forceinline__ unsigned pack_bf16(float a, float b) {
    unsigned au = __builtin_bit_cast(unsigned, a) + 0x8000u;
    unsigned bu = __builtin_bit_cast(unsigned, b) + 0x8000u;
    return __builtin_amdgcn_perm(bu, au, 0x07060302u);  // bytes: b[3],b[2],a[3],a[2]
}

// ---------------- fused cast fp32 -> bf16 for x, W_qkv, W_out ----------------
// ranges are 256-thread-block aligned: no intra-block divergence.
__global__ void cast_all(const float* __restrict__ x, const float* __restrict__ wqkv,
                         const float* __restrict__ wout,
                         bf16* __restrict__ xb, bf16* __restrict__ wqkvb,
                         bf16* __restrict__ woutb) {
    int i = blockIdx.x * blockDim.x + threadIdx.x;   // 0 .. 2097151 (x4 elems)
    const float4* s; short4* d; int o;
    if (i < 1048576)               { s = (const float4*)x;    d = (short4*)xb;    o = i; }
    else if (i < 1835008)          { s = (const float4*)wqkv; d = (short4*)wqkvb; o = i - 1048576; }
    else                           { s = (const float4*)wout; d = (short4*)woutb; o = i - 1835008; }
    float4 f = s[o];
    short4 v;
    v.x = f2bf(f.x); v.y = f2bf(f.y); v.z = f2bf(f.z); v.w = f2bf(f.w);
    d[o] = v;
}

// ---------- GEMM 128x128: C[M,Nc] = A[M,K] @ Bt[Nc,K]^T (both K-major) -------
// global_load_lds width=16, XOR-swizzled LDS slots, double-buffered.
// EPI=0: scatter to q/k/v [b,h,n,dh] (q pre-scaled). EPI=1: fp32 C.
template<int EPI>
__global__ __launch_bounds__(256)
void gemm128(const bf16* __restrict__ A, const bf16* __restrict__ Bt,
             float* __restrict__ Cf,
             bf16* __restrict__ qp, bf16* __restrict__ kp, bf16* __restrict__ vp,
             int K, int Ncols) {
    __shared__ alignas(16) short As[2][4096];   // 8 KB/buf
    __shared__ alignas(16) short Bs[2][4096];

    const int tid = threadIdx.x;
    const int wave = tid >> 6, lane = tid & 63;
    const int quad = lane >> 4, l16 = lane & 15;
    const int wm = wave >> 1, wn = wave & 1;
    const int m0 = blockIdx.x * 128;
    const int n0 = blockIdx.y * 128;

    f32x4 acc[4][4] = {};

    const int srow = tid >> 2;
    const int skk  = (((tid & 3) ^ ((tid >> 3) & 3))) * 8;
    const bf16* Ag = A  + (size_t)(m0 + srow) * K + skk;
    const bf16* Bg = Bt + (size_t)(n0 + srow) * K + skk;
    const size_t rowskip = (size_t)64 * K;
    short* Asl = &As[0][0] + tid * 8;
    short* Bsl = &Bs[0][0] + tid * 8;

    const int xk = (quad ^ ((l16 >> 1) & 3)) * 8;
    const int arow = wm * 64 + l16;
    const int brow = wn * 64 + l16;

    const int KI = K >> 5;
    glds16(Ag, Asl);
    glds16(Ag + rowskip, Asl + 2048);
    glds16(Bg, Bsl);
    glds16(Bg + rowskip, Bsl + 2048);
    __syncthreads();

    int buf = 0;
    for (int ki = 0; ki < KI; ++ki) {
        if (ki + 1 < KI) {
            const bf16* ag = Ag + (ki + 1) * 32;
            const bf16* bg = Bg + (ki + 1) * 32;
            short* ad = Asl + (buf ^ 1) * 4096;
            short* bd = Bsl + (buf ^ 1) * 4096;
            glds16(ag, ad);
            glds16(ag + rowskip, ad + 2048);
            glds16(bg, bd);
            glds16(bg + rowskip, bd + 2048);
        }
        const short* ab = &As[buf][0];
        const short* bb = &Bs[buf][0];
        bf16x8 af[4], bf[4];
        #pragma unroll
        for (int mt = 0; mt < 4; ++mt)
            af[mt] = *reinterpret_cast<const bf16x8*>(ab + (arow + mt * 16) * 32 + xk);
        #pragma unroll
        for (int nt = 0; nt < 4; ++nt)
            bf[nt] = *reinterpret_cast<const bf16x8*>(bb + (brow + nt * 16) * 32 + xk);
        #pragma unroll
        for (int mt = 0; mt < 4; ++mt)
            #pragma unroll
            for (int nt = 0; nt < 4; ++nt)
                acc[mt][nt] = __builtin_amdgcn_mfma_f32_16x16x32_bf16(
                    af[mt], bf[nt], acc[mt][nt], 0, 0, 0);
        __syncthreads();
        buf ^= 1;
    }

    #pragma unroll
    for (int mt = 0; mt < 4; ++mt) {
        #pragma unroll
        for (int nt = 0; nt < 4; ++nt) {
            #pragma unroll
            for (int r = 0; r < 4; ++r) {
                int gm = m0 + wm * 64 + mt * 16 + quad * 4 + r;
                int gn = n0 + wn * 64 + nt * 16 + l16;
                float val = acc[mt][nt][r];
                if (EPI == 0) {
                    int sel = gn >> 10, rem = gn & 1023;
                    int h = rem >> 6, dh = rem & 63;
                    int b = gm >> 11, nq = gm & 2047;
                    if (sel == 0) val *= QSCALE;
                    bf16* dst = (sel == 0) ? qp : ((sel == 1) ? kp : vp);
                    dst[((((size_t)b * 16 + h) * 2048) + nq) * 64 + dh] = __float2bfloat16(val);
                } else {
                    Cf[(size_t)gm * Ncols + gn] = val;
                }
            }
        }
    }
}

// ---------------- flash attention (causal), S^T form, 128-row q-tiles --------
// grid (32 bh, 16 y->qt), block 256 = 4 waves. Wave w owns TWO q-strips:
// A = rows Q0+16w..+16, B = rows Q0+64+16w..+16; lane (quad,l16) owns one
// q-row per strip. K/V LDS A-frags are shared by both strips (B-frags Q/P in
// regs). Static-max softmax. Main loop j0<Q0 full both strips; tail1 (j0=Q0)
// diag-A + full-B; tail2 (j0=Q0+64) diag-B.
__global__ __launch_bounds__(256)
void flash_attn(const bf16* __restrict__ Q, const bf16* __restrict__ K,
                const bf16* __restrict__ V, bf16* __restrict__ O) {
    __shared__ alignas(16) short Ks[2][64][72];   // [buf][key][dh], +8 pad
    __shared__ alignas(16) short Vt[2][64][68];   // [buf][dh][key]

    const int tid = threadIdx.x;
    const int wave = tid >> 6, lane = tid & 63;
    const int quad = lane >> 4, l16 = lane & 15;
    const int bh = blockIdx.x;
    const int yy = blockIdx.y;
    const int qt = (yy < 8) ? yy : (15 - (yy & 7));   // pair y,y+8 -> 34 iters/CU
    const int Q0 = qt * 128;
    const float NEG_INF = -__builtin_inff();

    const bf16* Qb = Q + (size_t)bh * 2048 * 64;
    const bf16* Kb = K + (size_t)bh * 2048 * 64;
    const bf16* Vb = V + (size_t)bh * 2048 * 64;

    // Q B-frags for both strips
    const int qrowA = Q0 + wave * 16 + l16;
    const int qrowB = qrowA + 64;
    const bf16x8 qfA0 = *reinterpret_cast<const bf16x8*>(Qb + (size_t)qrowA * 64 + quad * 8);
    const bf16x8 qfA1 = *reinterpret_cast<const bf16x8*>(Qb + (size_t)qrowA * 64 + 32 + quad * 8);
    const bf16x8 qfB0 = *reinterpret_cast<const bf16x8*>(Qb + (size_t)qrowB * 64 + quad * 8);
    const bf16x8 qfB1 = *reinterpret_cast<const bf16x8*>(Qb + (size_t)qrowB * 64 + 32 + quad * 8);

    float lA = 0.f, lB = 0.f;
    f32x4 oA[4] = {}, oB[4] = {};

    const int krow = tid >> 2;
    const int kcol = (tid & 3) * 16;
    const int kb = (tid & 15) * 4;
    const int db = (tid >> 4) * 4;

    {   // prologue: stage K/V tile j0=0 into buf 0
        bf16x8 a0 = *reinterpret_cast<const bf16x8*>(Kb + (size_t)krow * 64 + kcol);
        bf16x8 a1 = *reinterpret_cast<const bf16x8*>(Kb + (size_t)krow * 64 + kcol + 8);
        bf16x4 L0 = *reinterpret_cast<const bf16x4*>(Vb + (size_t)(kb + 0) * 64 + db);
        bf16x4 L1 = *reinterpret_cast<const bf16x4*>(Vb + (size_t)(kb + 1) * 64 + db);
        bf16x4 L2 = *reinterpret_cast<const bf16x4*>(Vb + (size_t)(kb + 2) * 64 + db);
        bf16x4 L3 = *reinterpret_cast<const bf16x4*>(Vb + (size_t)(kb + 3) * 64 + db);
        *reinterpret_cast<bf16x8*>(&Ks[0][krow][kcol]) = a0;
        *reinterpret_cast<bf16x8*>(&Ks[0][krow][kcol + 8]) = a1;
        #pragma unroll
        for (int j = 0; j < 4; ++j) {
            bf16x4 w; w[0] = L0[j]; w[1] = L1[j]; w[2] = L2[j]; w[3] = L3[j];
            *reinterpret_cast<bf16x4*>(&Vt[0][db + j][kb]) = w;
        }
    }
    __syncthreads();

    int buf = 0;
    // ---- main loop: j0 < Q0, both strips full ----
    for (int j0 = 0; j0 < Q0; j0 += 64) {
        const bf16* Kn = Kb + (size_t)(j0 + 64) * 64;
        const bf16* Vn = Vb + (size_t)(j0 + 64) * 64;
        bf16x8 nk0 = *reinterpret_cast<const bf16x8*>(Kn + (size_t)krow * 64 + kcol);
        bf16x8 nk1 = *reinterpret_cast<const bf16x8*>(Kn + (size_t)krow * 64 + kcol + 8);
        bf16x4 N0 = *reinterpret_cast<const bf16x4*>(Vn + (size_t)(kb + 0) * 64 + db);
        bf16x4 N1 = *reinterpret_cast<const bf16x4*>(Vn + (size_t)(kb + 1) * 64 + db);
        bf16x4 N2 = *reinterpret_cast<const bf16x4*>(Vn + (size_t)(kb + 2) * 64 + db);
        bf16x4 N3 = *reinterpret_cast<const bf16x4*>(Vn + (size_t)(kb + 3) * 64 + db);

        bf16x4 pkA[4], pkB[4];
        #pragma unroll
        for (int t = 0; t < 4; ++t) {
            bf16x8 k0 = *reinterpret_cast<const bf16x8*>(&Ks[buf][16 * t + l16][quad * 8]);
            bf16x8 k1 = *reinterpret_cast<const bf16x8*>(&Ks[buf][16 * t + l16][32 + quad * 8]);
            f32x4 sA = {}, sB = {};
            sA = __builtin_amdgcn_mfma_f32_16x16x32_bf16(k0, qfA0, sA, 0, 0, 0);
            sA = __builtin_amdgcn_mfma_f32_16x16x32_bf16(k1, qfA1, sA, 0, 0, 0);
            sB = __builtin_amdgcn_mfma_f32_16x16x32_bf16(k0, qfB0, sB, 0, 0, 0);
            sB = __builtin_amdgcn_mfma_f32_16x16x32_bf16(k1, qfB1, sB, 0, 0, 0);
            float a0 = __builtin_amdgcn_exp2f(sA[0]);
            float a1 = __builtin_amdgcn_exp2f(sA[1]);
            float a2 = __builtin_amdgcn_exp2f(sA[2]);
            float a3 = __builtin_amdgcn_exp2f(sA[3]);
            float b0 = __builtin_amdgcn_exp2f(sB[0]);
            float b1 = __builtin_amdgcn_exp2f(sB[1]);
            float b2 = __builtin_amdgcn_exp2f(sB[2]);
            float b3 = __builtin_amdgcn_exp2f(sB[3]);
            lA += (a0 + a1) + (a2 + a3);
            lB += (b0 + b1) + (b2 + b3);
            unsigned* pa = reinterpret_cast<unsigned*>(&pkA[t]);
            pa[0] = pack_bf16(a0, a1); pa[1] = pack_bf16(a2, a3);
            unsigned* pb = reinterpret_cast<unsigned*>(&pkB[t]);
            pb[0] = pack_bf16(b0, b1); pb[1] = pack_bf16(b2, b3);
        }

        #pragma unroll
        for (int t = 0; t < 4; ++t) {
            #pragma unroll
            for (int dt = 0; dt < 4; ++dt) {
                bf16x4 vf = *reinterpret_cast<const bf16x4*>(
                    &Vt[buf][dt * 16 + l16][t * 16 + quad * 4]);
                oA[dt] = __builtin_amdgcn_mfma_f32_16x16x16bf16_1k(vf, pkA[t], oA[dt], 0, 0, 0);
                oB[dt] = __builtin_amdgcn_mfma_f32_16x16x16bf16_1k(vf, pkB[t], oB[dt], 0, 0, 0);
            }
        }

        *reinterpret_cast<bf16x8*>(&Ks[buf ^ 1][krow][kcol]) = nk0;
        *reinterpret_cast<bf16x8*>(&Ks[buf ^ 1][krow][kcol + 8]) = nk1;
        #pragma unroll
        for (int j = 0; j < 4; ++j) {
            bf16x4 w; w[0] = N0[j]; w[1] = N1[j]; w[2] = N2[j]; w[3] = N3[j];
            *reinterpret_cast<bf16x4*>(&Vt[buf ^ 1][db + j][kb]) = w;
        }
        __syncthreads();
        buf ^= 1;
    }

    // ---- tail 1: j0 = Q0. Strip A diagonal (t<=wave), strip B full. ----
    {
        // prefetch tile Q0+64 for tail 2 (Q0+64 <= 1984, always valid)
        const bf16* Kn = Kb + (size_t)(Q0 + 64) * 64;
        const bf16* Vn = Vb + (size_t)(Q0 + 64) * 64;
        bf16x8 nk0 = *reinterpret_cast<const bf16x8*>(Kn + (size_t)krow * 64 + kcol);
        bf16x8 nk1 = *reinterpret_cast<const bf16x8*>(Kn + (size_t)krow * 64 + kcol + 8);
        bf16x4 N0 = *reinterpret_cast<const bf16x4*>(Vn + (size_t)(kb + 0) * 64 + db);
        bf16x4 N1 = *reinterpret_cast<const bf16x4*>(Vn + (size_t)(kb + 1) * 64 + db);
        bf16x4 N2 = *reinterpret_cast<const bf16x4*>(Vn + (size_t)(kb + 2) * 64 + db);
        bf16x4 N3 = *reinterpret_cast<const bf16x4*>(Vn + (size_t)(kb + 3) * 64 + db);

        bf16x4 pkA[4], pkB[4];
        #pragma unroll
        for (int t = 0; t < 4; ++t) {
            bf16x8 k0 = *reinterpret_cast<const bf16x8*>(&Ks[buf][16 * t + l16][quad * 8]);
            bf16x8 k1 = *reinterpret_cast<const bf16x8*>(&Ks[buf][16 * t + l16][32 + quad * 8]);
            f32x4 sB = {};
            sB = __builtin_amdgcn_mfma_f32_16x16x32_bf16(k0, qfB0, sB, 0, 0, 0);
            sB = __builtin_amdgcn_mfma_f32_16x16x32_bf16(k1, qfB1, sB, 0, 0, 0);
            float b0 = __builtin_amdgcn_exp2f(sB[0]);
            float b1 = __builtin_amdgcn_exp2f(sB[1]);
            float b2 = __builtin_amdgcn_exp2f(sB[2]);
            float b3 = __builtin_amdgcn_exp2f(sB[3]);
            lB += (b0 + b1) + (b2 + b3);
            unsigned* pb = reinterpret_cast<unsigned*>(&pkB[t]);
            pb[0] = pack_bf16(b0, b1); pb[1] = pack_bf16(b2, b3);
            if (t <= wave) {
                f32x4 sA = {};
                sA = __builtin_amdgcn_mfma_f32_16x16x32_bf16(k0, qfA0, sA, 0, 0, 0);
                sA = __builtin_amdgcn_mfma_f32_16x16x32_bf16(k1, qfA1, sA, 0, 0, 0);
                if (t == wave) {
                    #pragma unroll
                    for (int r = 0; r < 4; ++r)
                        if (quad * 4 + r > l16) sA[r] = NEG_INF;   // key > qrow
                }
                float a0 = __builtin_amdgcn_exp2f(sA[0]);   // exp2(-inf)=0
                float a1 = __builtin_amdgcn_exp2f(sA[1]);
                float a2 = __builtin_amdgcn_exp2f(sA[2]);
                float a3 = __builtin_amdgcn_exp2f(sA[3]);
                lA += (a0 + a1) + (a2 + a3);
                unsigned* pa = reinterpret_cast<unsigned*>(&pkA[t]);
                pa[0] = pack_bf16(a0, a1); pa[1] = pack_bf16(a2, a3);
            }
        }
        #pragma unroll
        for (int t = 0; t < 4; ++t) {
            #pragma unroll
            for (int dt = 0; dt < 4; ++dt) {
                bf16x4 vf = *reinterpret_cast<const bf16x4*>(
                    &Vt[buf][dt * 16 + l16][t * 16 + quad * 4]);
                oB[dt] = __builtin_amdgcn_mfma_f32_16x16x16bf16_1k(vf, pkB[t], oB[dt], 0, 0, 0);
                if (t <= wave)
                    oA[dt] = __builtin_amdgcn_mfma_f32_16x16x16bf16_1k(vf, pkA[t], oA[dt], 0, 0, 0);
            }
        }

        *reinterpret_cast<bf16x8*>(&Ks[buf ^ 1][krow][kcol]) = nk0;
        *reinterpret_cast<bf16x8*>(&Ks[buf ^ 1][krow][kcol + 8]) = nk1;
        #pragma unroll
        for (int j = 0; j < 4; ++j) {
            bf16x4 w; w[0] = N0[j]; w[1] = N1[j]; w[2] = N2[j]; w[3] = N3[j];
            *reinterpret_cast<bf16x4*>(&Vt[buf ^ 1][db + j][kb]) = w;
        }
        __syncthreads();
        buf ^= 1;
    }

    // ---- tail 2: j0 = Q0+64. Strip B diagonal only. ----
    {
        bf16x4 pkB[4];
        #pragma unroll
        for (int t = 0; t < 4; ++t) {
            if (t <= wave) {
                bf16x8 k0 = *reinterpret_cast<const bf16x8*>(&Ks[buf][16 * t + l16][quad * 8]);
                bf16x8 k1 = *reinterpret_cast<const bf16x8*>(&Ks[buf][16 * t + l16][32 + quad * 8]);
                f32x4 sB = {};
                sB = __builtin_amdgcn_mfma_f32_16x16x32_bf16(k0, qfB0, sB, 0, 0, 0);
                sB = __builtin_amdgcn_mfma_f32_16x16x32_bf16(k1, qfB1, sB, 0, 0, 0);
                if (t == wave) {
                    #pragma unroll
                    for (int r = 0; r < 4; ++r)
                        if (quad * 4 + r > l16) sB[r] = NEG_INF;
                }
                float b0 = __builtin_amdgcn_exp2f(sB[0]);
                float b1 = __builtin_amdgcn_exp2f(sB[1]);
                float b2 = __builtin_amdgcn_exp2f(sB[2]);
                float b3 = __builtin_amdgcn_exp2f(sB[3]);
                lB += (b0 + b1) + (b2 + b3);
                unsigned* pb = reinterpret_cast<unsigned*>(&pkB[t]);
                pb[0] = pack_bf16(b0, b1); pb[1] = pack_bf16(b2, b3);
            }
        }
        #pragma unroll
        for (int t = 0; t < 4; ++t) {
            if (t <= wave) {
                #pragma unroll
                for (int dt = 0; dt < 4; ++dt) {
                    bf16x4 vf = *reinterpret_cast<const bf16x4*>(
                        &Vt[buf][dt * 16 + l16][t * 16 + quad * 4]);
                    oB[dt] = __builtin_amdgcn_mfma_f32_16x16x16bf16_1k(vf, pkB[t], oB[dt], 0, 0, 0);
                }
            }
        }
    }

    // ---- reduce l across quads, normalize, store both strips ----
    lA += __shfl_xor(lA, 16, 64);
    lA += __shfl_xor(lA, 32, 64);
    lB += __shfl_xor(lB, 16, 64);
    lB += __shfl_xor(lB, 32, 64);
    const float invA = 1.f / lA;
    const float invB = 1.f / lB;

    const int b = bh >> 4, h = bh & 15;
    bf16* orowA = O + ((size_t)b * 2048 + qrowA) * 1024 + h * 64;
    bf16* orowB = O + ((size_t)b * 2048 + qrowB) * 1024 + h * 64;
    #pragma unroll
    for (int dt = 0; dt < 4; ++dt) {
        bf16x4 wA, wB;
        unsigned* ua = reinterpret_cast<unsigned*>(&wA);
        ua[0] = pack_bf16(oA[dt][0] * invA, oA[dt][1] * invA);
        ua[1] = pack_bf16(oA[dt][2] * invA, oA[dt][3] * invA);
        *reinterpret_cast<bf16x4*>(orowA + dt * 16 + quad * 4) = wA;
        unsigned* ub = reinterpret_cast<unsigned*>(&wB);
        ub[0] = pack_bf16(oB[dt][0] * invB, oB[dt][1] * invB);
        ub[1] = pack_bf16(oB[dt][2] * invB, oB[dt][3] * invB);
        *reinterpret_cast<bf16x4*>(orowB + dt * 16 + quad * 4) = wB;
    }
}

extern "C" void kernel_launch(void* const* d_in, const int* in_sizes, int n_in,
                              void* d_out, int out_size, void* d_ws, size_t ws_size,
                              hipStream_t stream) {
    const float* x    = (const float*)d_in[0];
    // d_in[1] = mask (int32 tril) — causal is hardcoded
    const float* Wqkv = (const float*)d_in[2];
    const float* Wout = (const float*)d_in[3];
    float* out = (float*)d_out;

    char* ws = (char*)d_ws;
    bf16* x_bf    = (bf16*)(ws);                  //  8 MB  [4096,1024]
    bf16* wqkv_bf = (bf16*)(ws + 8388608);        //  6 MB  [3072,1024]
    bf16* wout_bf = (bf16*)(ws + 14680064);       //  2 MB  [1024,1024]
    bf16* q       = (bf16*)(ws + 16777216);       //  8 MB  [32,2048,64] (pre-scaled)
    bf16* k       = (bf16*)(ws + 25165824);       //  8 MB
    bf16* v       = (bf16*)(ws + 33554432);       //  8 MB
    bf16* ao      = (bf16*)(ws + 41943040);       //  8 MB  [4096,1024]

    cast_all<<<8192, 256, 0, stream>>>(x, Wqkv, Wout, x_bf, wqkv_bf, wout_bf);
    gemm128<0><<<dim3(32, 24), 256, 0, stream>>>(x_bf, wqkv_bf, nullptr, q, k, v, 1024, 3072);
    flash_attn<<<dim3(32, 16), 256, 0, stream>>>(q, k, v, ao);
    gemm128<1><<<dim3(32, 8), 256, 0, stream>>>(ao, wout_bf, out, nullptr, nullptr, nullptr, 1024, 1024);
}